// Round 5
// baseline (135.443 us; speedup 1.0000x reference)
//
#include <hip/hip_runtime.h>
#include <math.h>

// DotProductAttention B=64,S=1024,D=64 fp32, bf16-MFMA flash attention.
// Round 4: occupancy + balance. Empirical law (r1-r3): blocks/CU =
// floor(64 KiB / LDS_block). BC=32 single-buffered tiles -> 14.5 KB -> 4
// blocks/CU. Single-buffer pipeline: fragment reads at iter top -> bar1 ->
// stage(it+1)+global load(it+2) overlap compute -> bar2. Work-stealing:
// grid 768 (3/CU), 1024 (batch,q0) items, atomic counter in d_ws covers
// the random-valid_len tail. Q frags in registers, exp2 softmax,
// perm-truncation bf16 packs.

#define BATCH 64
#define SEQ   1024
#define DIM   64
#define BQ    64            // queries per item (4 waves x 16)
#define BC    32            // keys per iteration
#define NKT   (SEQ / BC)    // 32
#define KSTR  72            // Ks row stride bf16 (144 B)
#define VSTR  40            // Vt row stride bf16 (80 B)
#define PSTR  40            // Ps row stride bf16 (80 B)
#define NITEMS (BATCH * (SEQ / BQ))   // 1024
#define GRID  768
#define QSCALE 0.18033688011112442f   // 0.125 * log2(e)
#define MASKED -1.0e6f

typedef __attribute__((ext_vector_type(8))) short bf16x8;
typedef __attribute__((ext_vector_type(4))) float f32x4;

__device__ __forceinline__ uint pack2_trunc(float lo, float hi) {
    return __builtin_amdgcn_perm(__float_as_uint(hi), __float_as_uint(lo), 0x07060302);
}
__device__ __forceinline__ ushort f2bf_rne(float x) {
    uint u = __float_as_uint(x);
    return (ushort)((u + 0x7fffu + ((u >> 16) & 1u)) >> 16);
}

__global__ __launch_bounds__(256, 3) void attn_mfma_flash4(
    const float* __restrict__ q, const float* __restrict__ k,
    const float* __restrict__ v, const int* __restrict__ valid_lens,
    float* __restrict__ out, unsigned* __restrict__ cnt)
{
    __shared__ ushort Ks[BC * KSTR];   // 4608 B  [key][d]
    __shared__ ushort Vt[DIM * VSTR];  // 5120 B  [d][key]
    __shared__ ushort Ps[BQ * PSTR];   // 5120 B  [query][key], wave-private bands
    __shared__ int next_item;

    const int t    = threadIdx.x;
    const int wave = t >> 6;
    const int wl   = t & 63;
    const int QD   = wl >> 4;
    const int li   = wl & 15;

    int item = blockIdx.x;
    while (item < NITEMS) {
        const int b  = item & 63;                 // consecutive items: different batches
        const int q0 = (item >> 6) * BQ;
        const int vl = valid_lens[b];
        const size_t boff = (size_t)b * SEQ * DIM;

        // ---- Q fragments into registers (B-operand), pre-scaled ----
        bf16x8 qb[2];
        {
            const float* qrow = q + boff + (size_t)(q0 + wave * 16 + li) * DIM + QD * 8;
            #pragma unroll
            for (int kc = 0; kc < 2; kc++) {
                float4 a = *(const float4*)(qrow + kc * 32);
                float4 c = *(const float4*)(qrow + kc * 32 + 4);
                union { bf16x8 v; ushort u[8]; } tmp;
                tmp.u[0] = f2bf_rne(a.x * QSCALE);
                tmp.u[1] = f2bf_rne(a.y * QSCALE);
                tmp.u[2] = f2bf_rne(a.z * QSCALE);
                tmp.u[3] = f2bf_rne(a.w * QSCALE);
                tmp.u[4] = f2bf_rne(c.x * QSCALE);
                tmp.u[5] = f2bf_rne(c.y * QSCALE);
                tmp.u[6] = f2bf_rne(c.z * QSCALE);
                tmp.u[7] = f2bf_rne(c.w * QSCALE);
                qb[kc] = tmp.v;
            }
        }

        const int it_max = (vl == 0) ? NKT : ((vl + BC - 1) / BC);

        float4 kf[2];     // next K tile: 2 coalesced float4/thread
        float  vf[8];     // next V tile: d=wl, keys wave*8..+7 (coalesced per j)

        auto load_tile = [&](int it) {
            const float4* kg = (const float4*)(k + boff + (size_t)it * BC * DIM);
            kf[0] = kg[t];
            kf[1] = kg[t + 256];
            const float* vgf = v + boff + (size_t)it * BC * DIM;
            #pragma unroll
            for (int j = 0; j < 8; j++)
                vf[j] = vgf[(size_t)(wave * 8 + j) * DIM + wl];
        };
        auto stage = [&]() {
            #pragma unroll
            for (int i = 0; i < 2; i++) {
                int idx = t + 256 * i;
                int row = idx >> 4, c4 = idx & 15;
                uint2 w;
                w.x = pack2_trunc(kf[i].x, kf[i].y);
                w.y = pack2_trunc(kf[i].z, kf[i].w);
                *(uint2*)&Ks[row * KSTR + c4 * 4] = w;
            }
            uint4 wv;
            wv.x = pack2_trunc(vf[0], vf[1]);
            wv.y = pack2_trunc(vf[2], vf[3]);
            wv.z = pack2_trunc(vf[4], vf[5]);
            wv.w = pack2_trunc(vf[6], vf[7]);
            *(uint4*)&Vt[wl * VSTR + wave * 8] = wv;   // b128, bank-floor uniform
        };

        float m_run = -INFINITY, l_run = 0.f;
        f32x4 acc[4];
        #pragma unroll
        for (int dt = 0; dt < 4; dt++) acc[dt] = (f32x4){0.f, 0.f, 0.f, 0.f};

        load_tile(0);
        stage();
        if (it_max > 1) load_tile(1);
        __syncthreads();

        for (int it = 0; it < it_max; it++) {
            // ---- all LDS fragment reads of tile `it` up front ----
            bf16x8 ka[2][2], vb[4];
            #pragma unroll
            for (int kt = 0; kt < 2; kt++) {
                ka[kt][0] = *(const bf16x8*)&Ks[(kt * 16 + li) * KSTR + QD * 8];
                ka[kt][1] = *(const bf16x8*)&Ks[(kt * 16 + li) * KSTR + 32 + QD * 8];
            }
            #pragma unroll
            for (int dt = 0; dt < 4; dt++)
                vb[dt] = *(const bf16x8*)&Vt[(dt * 16 + li) * VSTR + QD * 8];
            __syncthreads();   // bar1: reads drained (lgkmcnt) before overwrite

            // ---- staging + next-next global load overlap ALL compute ----
            if (it + 1 < it_max) stage();
            if (it + 2 < it_max) load_tile(it + 2);

            // ---- S^T = K x Q^T : rows = keys (QD*4+r), cols = queries (li) ----
            f32x4 sc[2];
            #pragma unroll
            for (int kt = 0; kt < 2; kt++) {
                f32x4 c = (f32x4){0.f, 0.f, 0.f, 0.f};
                c = __builtin_amdgcn_mfma_f32_16x16x32_bf16(ka[kt][0], qb[0], c, 0, 0, 0);
                c = __builtin_amdgcn_mfma_f32_16x16x32_bf16(ka[kt][1], qb[1], c, 0, 0, 0);
                sc[kt] = c;
            }

            const int kbase = it * BC;
            if (kbase + BC > vl) {
                #pragma unroll
                for (int kt = 0; kt < 2; kt++)
                    #pragma unroll
                    for (int r = 0; r < 4; r++) {
                        int key = kbase + kt * 16 + QD * 4 + r;
                        if (key >= vl) sc[kt][r] = MASKED;
                    }
            }

            // ---- online softmax, exp2 domain (row = query = li) ----
            float mt = -INFINITY;
            #pragma unroll
            for (int kt = 0; kt < 2; kt++)
                #pragma unroll
                for (int r = 0; r < 4; r++) mt = fmaxf(mt, sc[kt][r]);
            mt = fmaxf(mt, __shfl_xor(mt, 16, 64));
            mt = fmaxf(mt, __shfl_xor(mt, 32, 64));
            float mn = fmaxf(m_run, mt);
            float alpha = exp2f(m_run - mn);
            m_run = mn;

            float ls = 0.f;
            #pragma unroll
            for (int kt = 0; kt < 2; kt++) {
                float p0 = exp2f(sc[kt][0] - mn);
                float p1 = exp2f(sc[kt][1] - mn);
                float p2 = exp2f(sc[kt][2] - mn);
                float p3 = exp2f(sc[kt][3] - mn);
                ls += (p0 + p1) + (p2 + p3);
                uint2 w;
                w.x = pack2_trunc(p0, p1);
                w.y = pack2_trunc(p2, p3);
                *(uint2*)&Ps[(wave * 16 + li) * PSTR + kt * 16 + QD * 4] = w;
            }
            ls += __shfl_xor(ls, 16, 64);
            ls += __shfl_xor(ls, 32, 64);
            l_run = l_run * alpha + ls;

            float a0 = __shfl(alpha, QD * 4 + 0, 64);
            float a1 = __shfl(alpha, QD * 4 + 1, 64);
            float a2 = __shfl(alpha, QD * 4 + 2, 64);
            float a3 = __shfl(alpha, QD * 4 + 3, 64);
            #pragma unroll
            for (int dt = 0; dt < 4; dt++) {
                acc[dt][0] *= a0; acc[dt][1] *= a1;
                acc[dt][2] *= a2; acc[dt][3] *= a3;
            }

            // ---- PV: single K=32 mfma per d-tile; P via wave-private LDS ----
            bf16x8 pa = *(const bf16x8*)&Ps[(wave * 16 + li) * PSTR + QD * 8];
            #pragma unroll
            for (int dt = 0; dt < 4; dt++)
                acc[dt] = __builtin_amdgcn_mfma_f32_16x16x32_bf16(pa, vb[dt], acc[dt], 0, 0, 0);

            __syncthreads();   // bar2: staging visible for next iter's reads
        }

        // ---- epilogue: O /= l, fp32 store ----
        float invl = 1.0f / l_run;
        float i0 = __shfl(invl, QD * 4 + 0, 64);
        float i1 = __shfl(invl, QD * 4 + 1, 64);
        float i2 = __shfl(invl, QD * 4 + 2, 64);
        float i3 = __shfl(invl, QD * 4 + 3, 64);
        float* ob = out + boff + (size_t)q0 * DIM;
        const int rbase = wave * 16 + QD * 4;
        #pragma unroll
        for (int dt = 0; dt < 4; dt++) {
            int col = dt * 16 + li;
            ob[(size_t)(rbase + 0) * DIM + col] = acc[dt][0] * i0;
            ob[(size_t)(rbase + 1) * DIM + col] = acc[dt][1] * i1;
            ob[(size_t)(rbase + 2) * DIM + col] = acc[dt][2] * i2;
            ob[(size_t)(rbase + 3) * DIM + col] = acc[dt][3] * i3;
        }

        // ---- steal next item ----
        if (t == 0) next_item = GRID + (int)atomicAdd(cnt, 1u);
        __syncthreads();           // also fences LDS reuse for next item
        item = next_item;
    }
}

extern "C" void kernel_launch(void* const* d_in, const int* in_sizes, int n_in,
                              void* d_out, int out_size, void* d_ws, size_t ws_size,
                              hipStream_t stream) {
    const float* q = (const float*)d_in[0];
    const float* k = (const float*)d_in[1];
    const float* v = (const float*)d_in[2];
    const int* valid_lens = (const int*)d_in[3];
    float* out = (float*)d_out;
    unsigned* cnt = (unsigned*)d_ws;

    hipMemsetAsync(cnt, 0, sizeof(unsigned), stream);   // graph-capture-legal
    attn_mfma_flash4<<<dim3(GRID), dim3(256), 0, stream>>>(q, k, v, valid_lens, out, cnt);
}